// Round 8
// baseline (214.809 us; speedup 1.0000x reference)
//
#include <hip/hip_runtime.h>
#include <hip/hip_fp16.h>

typedef _Float16 half8 __attribute__((ext_vector_type(8)));
typedef float float4v __attribute__((ext_vector_type(4)));

// ================= preprocessing =================

__global__ void k_deg(const int* __restrict__ dst, int E, int* __restrict__ cnt) {
    int e = blockIdx.x * blockDim.x + threadIdx.x;
    if (e < E) atomicAdd(&cnt[dst[e]], 1);
}

__global__ void k_scanA(const int* __restrict__ cnt, int N, int* __restrict__ blockSums) {
    __shared__ int s[256];
    int t = threadIdx.x, i = blockIdx.x * 256 + t;
    s[t] = (i < N) ? cnt[i] : 0;
    __syncthreads();
    for (int o = 128; o > 0; o >>= 1) {
        if (t < o) s[t] += s[t + o];
        __syncthreads();
    }
    if (t == 0) blockSums[blockIdx.x] = s[0];
}

// exclusive scan of block sums + wfc precompute + pool zero (fused small kernel)
__global__ void k_scan2W(int* blockSums, int nb,
                         const float* __restrict__ W3, const float* __restrict__ fcW,
                         const float* __restrict__ b3, float* __restrict__ wfc,
                         double* __restrict__ pool) {
    __shared__ int s[256];
    int t = threadIdx.x;
    pool[t] = 0.0;
    if (t < 64) {                       // wfc[c] = (W3@fcW)[c]; wfc[64] = b3.fcW
        float v = 0.f;
        #pragma unroll 8
        for (int j = 0; j < 64; ++j) v += W3[t * 64 + j] * fcW[j];
        wfc[t] = v;
        float bb = b3[t] * fcW[t];
        for (int o = 32; o > 0; o >>= 1) bb += __shfl_down(bb, o, 64);
        if (t == 0) wfc[64] = bb;
    }
    s[t] = (t < nb) ? blockSums[t] : 0;
    __syncthreads();
    for (int o = 1; o < 256; o <<= 1) {
        int v = (t >= o) ? s[t - o] : 0;
        __syncthreads();
        s[t] += v;
        __syncthreads();
    }
    blockSums[t] = (t == 0) ? 0 : s[t - 1];
}

// rowptr / cursor / dinv / gx16 = fp16(dinv (.) x) padded to stride 16
__global__ void k_scanC(const int* __restrict__ cnt, int N, const int* __restrict__ blockOffs,
                        const float* __restrict__ x,
                        int* __restrict__ rowptr, int* __restrict__ cursor,
                        float* __restrict__ dinv, __half* __restrict__ gx) {
    __shared__ int s[256];
    int t = threadIdx.x, i = blockIdx.x * 256 + t;
    int d = (i < N) ? cnt[i] : 0;
    s[t] = d;
    __syncthreads();
    for (int o = 1; o < 256; o <<= 1) {
        int v = (t >= o) ? s[t - o] : 0;
        __syncthreads();
        s[t] += v;
        __syncthreads();
    }
    if (i < N) {
        int p = blockOffs[blockIdx.x] + s[t] - d;
        rowptr[i] = p;
        cursor[i] = p;
        float di = 1.0f / sqrtf((float)(d + 1));
        dinv[i] = di;
        #pragma unroll
        for (int k = 0; k < 16; ++k)
            gx[i * 16 + k] = __float2half(k < 10 ? x[i * 10 + k] * di : 0.f);
        if (i == N - 1) rowptr[N] = p + d;
    }
}

// XCD-pinned CSR fill: range r = b&7 (round-robin block->XCD); col writes land in a
// ~400KB L2-resident slice per XCD.
__global__ void k_fillX(const int* __restrict__ src, const int* __restrict__ dst, int E,
                        int* __restrict__ cursor, int* __restrict__ col, int Q) {
    int b = blockIdx.x;
    int r = b & 7;
    int e = (b >> 3) * 256 + threadIdx.x;
    if (e >= E) return;
    int d = dst[e];
    int lo = r * Q;
    if (d < lo || d >= lo + Q) return;
    int pos = atomicAdd(&cursor[d], 1);
    col[pos] = src[e];
}

// ================= layer 1: gather gx16 (1.6MB, L2-resident), 16 lanes/node =================
__global__ void k_L1(const __half* __restrict__ gx, const float* __restrict__ W1,
                     const float* __restrict__ b1, const int* __restrict__ rowptr,
                     const int* __restrict__ col, const float* __restrict__ dinv,
                     __half* __restrict__ g1, int N) {
    __shared__ float sW[10 * 64];
    __shared__ float sB[64];
    int t = threadIdx.x;
    for (int i = t; i < 640; i += 256) sW[i] = W1[i];
    if (t < 64) sB[t] = b1[t];
    __syncthreads();
    int node = blockIdx.x * 16 + (t >> 4);
    int f = t & 15;
    bool live = node < N;
    bool act = live && (f < 10);
    const char* gp = (const char*)gx;
    unsigned fo = (unsigned)(f << 1);
    float di = live ? dinv[node] : 0.f;
    float a = act ? __half2float(*(const __half*)(gp + ((unsigned)node << 5) + fo)) : 0.f;
    int s0 = 0, s1 = 0;
    if (live) { s0 = rowptr[node]; s1 = rowptr[node + 1]; }
    int e = s0;
    for (; e + 8 <= s1; e += 8) {
        int j0 = col[e],     j1 = col[e + 1], j2 = col[e + 2], j3 = col[e + 3];
        int j4 = col[e + 4], j5 = col[e + 5], j6 = col[e + 6], j7 = col[e + 7];
        float v0 = 0.f, v1 = 0.f, v2 = 0.f, v3 = 0.f, v4 = 0.f, v5 = 0.f, v6 = 0.f, v7 = 0.f;
        if (act) {
            v0 = __half2float(*(const __half*)(gp + ((unsigned)j0 << 5) + fo));
            v1 = __half2float(*(const __half*)(gp + ((unsigned)j1 << 5) + fo));
            v2 = __half2float(*(const __half*)(gp + ((unsigned)j2 << 5) + fo));
            v3 = __half2float(*(const __half*)(gp + ((unsigned)j3 << 5) + fo));
            v4 = __half2float(*(const __half*)(gp + ((unsigned)j4 << 5) + fo));
            v5 = __half2float(*(const __half*)(gp + ((unsigned)j5 << 5) + fo));
            v6 = __half2float(*(const __half*)(gp + ((unsigned)j6 << 5) + fo));
            v7 = __half2float(*(const __half*)(gp + ((unsigned)j7 << 5) + fo));
        }
        a += ((v0 + v1) + (v2 + v3)) + ((v4 + v5) + (v6 + v7));
    }
    for (; e < s1; ++e) {
        int j = col[e];
        if (act) a += __half2float(*(const __half*)(gp + ((unsigned)j << 5) + fo));
    }
    a *= di;                                   // P_i(x)[f], f<10
    int gb = t & 48;                           // group base lane within wave
    float c0 = 0.f, c1 = 0.f, c2 = 0.f, c3 = 0.f;
    int c4 = 4 * f;
    #pragma unroll
    for (int k = 0; k < 10; ++k) {
        float ak = __shfl(a, gb + k, 64);
        c0 += ak * sW[k * 64 + c4];
        c1 += ak * sW[k * 64 + c4 + 1];
        c2 += ak * sW[k * 64 + c4 + 2];
        c3 += ak * sW[k * 64 + c4 + 3];
    }
    if (!live) return;
    float h0 = di * fmaxf(c0 + sB[c4], 0.f);
    float h1 = di * fmaxf(c1 + sB[c4 + 1], 0.f);
    float h2 = di * fmaxf(c2 + sB[c4 + 2], 0.f);
    float h3 = di * fmaxf(c3 + sB[c4 + 3], 0.f);
    union { __half h[4]; uint2 u; } pk;
    pk.h[0] = __float2half(h0); pk.h[1] = __float2half(h1);
    pk.h[2] = __float2half(h2); pk.h[3] = __float2half(h3);
    *reinterpret_cast<uint2*>(&g1[(size_t)node * 64 + c4]) = pk.u;
}

// ================= layer 2: 16 nodes/block, vector gather + MFMA epilogue =================
__device__ __forceinline__ void acc4(float* a, uint2 u) {
    __half2 h0 = *reinterpret_cast<__half2*>(&u.x);
    __half2 h1 = *reinterpret_cast<__half2*>(&u.y);
    float2 f0 = __half22float2(h0), f1 = __half22float2(h1);
    a[0] += f0.x; a[1] += f0.y; a[2] += f1.x; a[3] += f1.y;
}

__global__ void __launch_bounds__(256) k_L2(
        const __half* __restrict__ g1, const float* __restrict__ W2,
        const float* __restrict__ b2, const float* __restrict__ wfc,
        const int* __restrict__ rowptr, const int* __restrict__ col,
        const float* __restrict__ dinv, float* __restrict__ tvec, int N) {
    __shared__ __half At[16 * 72];     // 16 nodes x 64 feats, stride 72 (bank-safe b128 reads)
    __shared__ float sRed[4][16];
    __shared__ float sDi[16];
    int t = threadIdx.x;
    int lane = t & 63, wid = t >> 6;
    int m = lane & 15, quad = lane >> 4;

    // ---- B fragments: W2 column cg, fp16 hi/lo split (registers, overlaps gather) ----
    int cg = (wid << 4) + m;
    half8 H0, L0, H1, L1;
    #pragma unroll
    for (int j = 0; j < 8; ++j) {
        float w0 = W2[(quad * 8 + j) * 64 + cg];
        _Float16 h0 = (_Float16)w0;
        H0[j] = h0; L0[j] = (_Float16)(w0 - (float)h0);
        float w1 = W2[(32 + quad * 8 + j) * 64 + cg];
        _Float16 h1 = (_Float16)w1;
        H1[j] = h1; L1[j] = (_Float16)(w1 - (float)h1);
    }
    float bc = b2[cg], wf = wfc[cg];

    // ---- gather: node nl = t>>4 (16/block), lane f4 = t&15 handles 4 feats ----
    int nl = t >> 4, f4 = t & 15;
    int node = blockIdx.x * 16 + nl;
    bool live = node < N;
    float di = live ? dinv[node] : 0.f;
    const char* gp = (const char*)g1;
    unsigned fo = (unsigned)(f4 << 3);
    float a[4] = {0.f, 0.f, 0.f, 0.f};
    if (live) {
        acc4(a, *(const uint2*)(gp + ((unsigned)node << 7) + fo));  // self loop
        int s0 = rowptr[node], s1 = rowptr[node + 1];
        int e = s0;
        for (; e + 8 <= s1; e += 8) {
            int j0 = col[e],     j1 = col[e + 1], j2 = col[e + 2], j3 = col[e + 3];
            int j4 = col[e + 4], j5 = col[e + 5], j6 = col[e + 6], j7 = col[e + 7];
            uint2 u0 = *(const uint2*)(gp + ((unsigned)j0 << 7) + fo);
            uint2 u1 = *(const uint2*)(gp + ((unsigned)j1 << 7) + fo);
            uint2 u2 = *(const uint2*)(gp + ((unsigned)j2 << 7) + fo);
            uint2 u3 = *(const uint2*)(gp + ((unsigned)j3 << 7) + fo);
            uint2 u4 = *(const uint2*)(gp + ((unsigned)j4 << 7) + fo);
            uint2 u5 = *(const uint2*)(gp + ((unsigned)j5 << 7) + fo);
            uint2 u6 = *(const uint2*)(gp + ((unsigned)j6 << 7) + fo);
            uint2 u7 = *(const uint2*)(gp + ((unsigned)j7 << 7) + fo);
            acc4(a, u0); acc4(a, u1); acc4(a, u2); acc4(a, u3);
            acc4(a, u4); acc4(a, u5); acc4(a, u6); acc4(a, u7);
        }
        for (; e < s1; ++e)
            acc4(a, *(const uint2*)(gp + ((unsigned)col[e] << 7) + fo));
    }
    union { __half h[4]; uint2 u; } pk;
    pk.h[0] = __float2half(a[0] * di); pk.h[1] = __float2half(a[1] * di);
    pk.h[2] = __float2half(a[2] * di); pk.h[3] = __float2half(a[3] * di);
    *reinterpret_cast<uint2*>(&At[nl * 72 + f4 * 4]) = pk.u;
    if (f4 == 0) sDi[nl] = di;
    __syncthreads();

    // ---- MFMA: D[m=node][n=col] = A(16x64) @ W2(64x64); this wave: cols 16*wid.. ----
    half8 A0 = *reinterpret_cast<const half8*>(&At[m * 72 + quad * 8]);
    half8 A1 = *reinterpret_cast<const half8*>(&At[m * 72 + 32 + quad * 8]);
    float4v C = {0.f, 0.f, 0.f, 0.f};
    C = __builtin_amdgcn_mfma_f32_16x16x32_f16(A0, H0, C, 0, 0, 0);
    C = __builtin_amdgcn_mfma_f32_16x16x32_f16(A0, L0, C, 0, 0, 0);
    C = __builtin_amdgcn_mfma_f32_16x16x32_f16(A1, H1, C, 0, 0, 0);
    C = __builtin_amdgcn_mfma_f32_16x16x32_f16(A1, L1, C, 0, 0, 0);

    // ---- epilogue: relu(C+b2)*wfc, reduce over cols -> per-node scalar ----
    float v0 = fmaxf(C[0] + bc, 0.f) * wf;
    float v1 = fmaxf(C[1] + bc, 0.f) * wf;
    float v2 = fmaxf(C[2] + bc, 0.f) * wf;
    float v3 = fmaxf(C[3] + bc, 0.f) * wf;
    #pragma unroll
    for (int o = 1; o < 16; o <<= 1) {
        v0 += __shfl_xor(v0, o, 64);
        v1 += __shfl_xor(v1, o, 64);
        v2 += __shfl_xor(v2, o, 64);
        v3 += __shfl_xor(v3, o, 64);
    }
    if (m == 0) {
        sRed[wid][quad * 4 + 0] = v0;
        sRed[wid][quad * 4 + 1] = v1;
        sRed[wid][quad * 4 + 2] = v2;
        sRed[wid][quad * 4 + 3] = v3;
    }
    __syncthreads();
    if (t < 16) {
        int ng = blockIdx.x * 16 + t;
        if (ng < N) {
            float tt = sRed[0][t] + sRed[1][t] + sRed[2][t] + sRed[3][t];
            tvec[ng] = sDi[t] * tt;            // t_j = dinv_j * (h2_j . wfc)
        }
    }
}

// ================= layer 3: scalar gather over tvec (200KB) + mean-pool =================
__global__ void k_agg3(const float* __restrict__ tvec, const int* __restrict__ rowptr,
                       const int* __restrict__ col, const float* __restrict__ dinv,
                       double* __restrict__ pool, int N) {
    int tid = blockIdx.x * 256 + threadIdx.x;
    int node = tid >> 4, lane = tid & 15;
    if (node >= N) return;
    int s0 = rowptr[node], s1 = rowptr[node + 1];
    const char* tp = (const char*)tvec;
    float s = 0.f;
    for (int e = s0 + lane; e < s1; e += 16)
        s += *(const float*)(tp + ((unsigned)col[e] << 2));
    #pragma unroll
    for (int o = 1; o < 16; o <<= 1) s += __shfl_xor(s, o, 64);
    if (lane == 0) {
        double contrib = (double)(dinv[node] * (tvec[node] + s));
        atomicAdd(&pool[node & 255], contrib);
    }
}

__global__ void k_final(const double* __restrict__ pool, const float* __restrict__ wfc,
                        const float* __restrict__ fcb, float* __restrict__ out, double invN) {
    __shared__ double s[256];
    int t = threadIdx.x;
    s[t] = pool[t];
    __syncthreads();
    for (int o = 128; o > 0; o >>= 1) {
        if (t < o) s[t] += s[t + o];
        __syncthreads();
    }
    if (t == 0) out[0] = (float)(s[0] * invN) + wfc[64] + fcb[0];
}

extern "C" void kernel_launch(void* const* d_in, const int* in_sizes, int n_in,
                              void* d_out, int out_size, void* d_ws, size_t ws_size,
                              hipStream_t stream) {
    const float* x   = (const float*)d_in[0];
    const int*   ei  = (const int*)d_in[1];
    const float* W1  = (const float*)d_in[2];
    const float* b1  = (const float*)d_in[3];
    const float* W2  = (const float*)d_in[4];
    const float* b2  = (const float*)d_in[5];
    const float* W3  = (const float*)d_in[6];
    const float* b3  = (const float*)d_in[7];
    const float* fcW = (const float*)d_in[8];
    const float* fcb = (const float*)d_in[9];

    const int N = in_sizes[0] / 10;
    const int E = in_sizes[1] / 2;
    const int* src = ei;
    const int* dst = ei + E;

    // ---- workspace carve-up (256B aligned) ----
    char* w = (char*)d_ws;
    size_t off = 0;
    auto alloc = [&](size_t bytes) -> void* {
        void* p = w + off;
        off += (bytes + 255) & ~(size_t)255;
        return p;
    };
    int*    cnt       = (int*)alloc((size_t)N * 4);
    size_t  zeroBytes = off;                         // memset covers cnt only
    double* pool      = (double*)alloc(256 * 8);     // zeroed in k_scan2W
    float*  dinv      = (float*)alloc((size_t)N * 4);
    int*    rowptr    = (int*)alloc((size_t)(N + 1) * 4);
    int*    cursor    = (int*)alloc((size_t)N * 4);
    int*    col       = (int*)alloc((size_t)E * 4);
    int*    blockSums = (int*)alloc(256 * 4);
    float*  wfc       = (float*)alloc(65 * 4);
    float*  tvec      = (float*)alloc((size_t)N * 4);
    __half* gx        = (__half*)alloc((size_t)N * 16 * 2);   // stride-16 padded
    __half* g1        = (__half*)alloc((size_t)N * 64 * 2);
    (void)ws_size; (void)n_in; (void)out_size;

    const int nbScan   = (N + 255) / 256;
    const int nbEdges  = (E + 255) / 256;
    const int nbNode16 = (N + 15) / 16;       // 16 nodes per 256-block
    const int Q8       = (N + 7) / 8;         // dst-range width for XCD-pinned fill

    // ---- preprocessing ----
    hipMemsetAsync(cnt, 0, zeroBytes, stream);
    k_deg   <<<nbEdges, 256, 0, stream>>>(dst, E, cnt);
    k_scanA <<<nbScan, 256, 0, stream>>>(cnt, N, blockSums);
    k_scan2W<<<1, 256, 0, stream>>>(blockSums, nbScan, W3, fcW, b3, wfc, pool);
    k_scanC <<<nbScan, 256, 0, stream>>>(cnt, N, blockSums, x, rowptr, cursor, dinv, gx);
    k_fillX <<<nbEdges * 8, 256, 0, stream>>>(src, dst, E, cursor, col, Q8);

    // ---- fused layers ----
    k_L1<<<nbNode16, 256, 0, stream>>>(gx, W1, b1, rowptr, col, dinv, g1, N);
    k_L2<<<nbNode16, 256, 0, stream>>>(g1, W2, b2, wfc, rowptr, col, dinv, tvec, N);
    k_agg3<<<nbNode16, 256, 0, stream>>>(tvec, rowptr, col, dinv, pool, N);
    k_final<<<1, 256, 0, stream>>>(pool, wfc, fcb, (float*)d_out, 1.0 / (double)N);
}